// Round 1
// baseline (1312.263 us; speedup 1.0000x reference)
//
#include <hip/hip_runtime.h>
#include <hip/hip_bf16.h>

#define D_MODEL 2048
#define N_HEADS 16
#define HEAD_DIM 128
#define D_FF 8192
#define BATCH 2
#define SEQ 2048
#define M_TOK (BATCH * SEQ)

typedef __attribute__((ext_vector_type(8))) short short8;
typedef __attribute__((ext_vector_type(4))) float f32x4;

__device__ __forceinline__ unsigned short f2b(float f) {
  __hip_bfloat16 h = __float2bfloat16(f);
  return *reinterpret_cast<unsigned short*>(&h);
}
__device__ __forceinline__ float b2f(unsigned short u) {
  unsigned int x = ((unsigned int)u) << 16;
  return __uint_as_float(x);
}

__device__ __forceinline__ void gload_lds16(const void* gsrc, void* ldst) {
  __builtin_amdgcn_global_load_lds(
      (const __attribute__((address_space(1))) void*)gsrc,
      (__attribute__((address_space(3))) void*)ldst, 16, 0, 0);
}

// ---------------- f32 -> bf16 convert (grid-stride, 8 elems/thread) ----------
__global__ __launch_bounds__(256)
void cvt_kernel(const float* __restrict__ src, unsigned short* __restrict__ dst,
                int nchunks) {
  int i = blockIdx.x * blockDim.x + threadIdx.x;
  int stride = gridDim.x * blockDim.x;
  for (int c = i; c < nchunks; c += stride) {
    const float4 a = *(const float4*)(src + (size_t)c * 8);
    const float4 b = *(const float4*)(src + (size_t)c * 8 + 4);
    short8 r;
    r[0] = f2b(a.x); r[1] = f2b(a.y); r[2] = f2b(a.z); r[3] = f2b(a.w);
    r[4] = f2b(b.x); r[5] = f2b(b.y); r[6] = f2b(b.z); r[7] = f2b(b.w);
    *(short8*)(dst + (size_t)c * 8) = r;
  }
}

// ---------------- bq_eff = bq + rotary[n & 127] ------------------------------
__global__ void bqrot_kernel(const float* __restrict__ bq,
                             const float* __restrict__ rot,
                             float* __restrict__ outp) {
  int i = blockIdx.x * 256 + threadIdx.x;
  if (i < D_MODEL) outp[i] = bq[i] + rot[i & (HEAD_DIM - 1)];
}

// ---------------- RMSNorm: f32 in -> bf16 out, one block per row -------------
__global__ __launch_bounds__(256)
void rmsnorm_kernel(const float* __restrict__ x, const float* __restrict__ wv,
                    unsigned short* __restrict__ outp) {
  const int row = blockIdx.x;
  const float* xr = x + (size_t)row * D_MODEL;
  const int base = threadIdx.x * 8;
  float4 a = *(const float4*)(xr + base);
  float4 c = *(const float4*)(xr + base + 4);
  float ss = a.x * a.x + a.y * a.y + a.z * a.z + a.w * a.w +
             c.x * c.x + c.y * c.y + c.z * c.z + c.w * c.w;
#pragma unroll
  for (int m = 1; m < 64; m <<= 1) ss += __shfl_xor(ss, m);
  __shared__ float red[4];
  if ((threadIdx.x & 63) == 0) red[threadIdx.x >> 6] = ss;
  __syncthreads();
  float tot = red[0] + red[1] + red[2] + red[3];
  float sc = rsqrtf(tot * (1.0f / D_MODEL) + 1e-8f);
  float4 w0 = *(const float4*)(wv + base);
  float4 w1 = *(const float4*)(wv + base + 4);
  short8 r;
  r[0] = f2b(a.x * sc * w0.x); r[1] = f2b(a.y * sc * w0.y);
  r[2] = f2b(a.z * sc * w0.z); r[3] = f2b(a.w * sc * w0.w);
  r[4] = f2b(c.x * sc * w1.x); r[5] = f2b(c.y * sc * w1.y);
  r[6] = f2b(c.z * sc * w1.z); r[7] = f2b(c.w * sc * w1.w);
  *(short8*)(outp + (size_t)row * D_MODEL + base) = r;
}

// ---------------- GEMM: C[M,N] = A[M,K] @ W[N,K]^T + bias (+res) -------------
// MODE 0: bf16 out, no residual.  MODE 1: f32 out, adds res[m,n].
template <int MODE>
__global__ __launch_bounds__(256)
void gemm_bt(const unsigned short* __restrict__ A, int lda,
             const unsigned short* __restrict__ W,
             const float* __restrict__ bias, const float* res, void* outp,
             int N, int K) {
  __shared__ unsigned short As[128 * 32];
  __shared__ unsigned short Bs[128 * 32];
  const int t = threadIdx.x;
  const int l = t & 63;
  const int w = t >> 6;
  const int m0 = blockIdx.y << 7;
  const int n0 = blockIdx.x << 7;
  const int wr = (w >> 1) << 6;
  const int wc = (w & 1) << 6;

  const unsigned short* Ab = A + (size_t)m0 * lda;
  const unsigned short* Wb = W + (size_t)n0 * K;

  f32x4 acc[4][4] = {};

  const int c0 = t, c1 = t + 256;
  const int ar0 = c0 >> 2, ak0 = (c0 & 3) * 8;
  const int ar1 = c1 >> 2, ak1 = (c1 & 3) * 8;
  const int lr = l & 15, lk = (l >> 4) * 8;

  for (int k0 = 0; k0 < K; k0 += 32) {
    gload_lds16(Ab + (size_t)ar0 * lda + k0 + ak0, &As[c0 * 8]);
    gload_lds16(Ab + (size_t)ar1 * lda + k0 + ak1, &As[c1 * 8]);
    gload_lds16(Wb + (size_t)ar0 * K + k0 + ak0, &Bs[c0 * 8]);
    gload_lds16(Wb + (size_t)ar1 * K + k0 + ak1, &Bs[c1 * 8]);
    __syncthreads();
    short8 a[4], b[4];
#pragma unroll
    for (int mi = 0; mi < 4; mi++)
      a[mi] = *(const short8*)&As[(wr + mi * 16 + lr) * 32 + lk];
#pragma unroll
    for (int ni = 0; ni < 4; ni++)
      b[ni] = *(const short8*)&Bs[(wc + ni * 16 + lr) * 32 + lk];
#pragma unroll
    for (int mi = 0; mi < 4; mi++)
#pragma unroll
      for (int ni = 0; ni < 4; ni++)
        acc[mi][ni] = __builtin_amdgcn_mfma_f32_16x16x32_bf16(
            a[mi], b[ni], acc[mi][ni], 0, 0, 0);
    __syncthreads();
  }

  const int lg = (l >> 4) * 4;
#pragma unroll
  for (int mi = 0; mi < 4; mi++) {
#pragma unroll
    for (int ni = 0; ni < 4; ni++) {
      int cn = n0 + wc + ni * 16 + lr;
      float bval = bias[cn];
#pragma unroll
      for (int j = 0; j < 4; j++) {
        int r = m0 + wr + mi * 16 + lg + j;
        float vv = acc[mi][ni][j] + bval;
        size_t idx = (size_t)r * N + cn;
        if (MODE == 1) {
          vv += res[idx];
          ((float*)outp)[idx] = vv;
        } else {
          ((unsigned short*)outp)[idx] = f2b(vv);
        }
      }
    }
  }
}

// ---------------- V transpose: v[(b*S+s)*D + h*128 + d] -> vt[(bh*128+d)*S + s]
__global__ __launch_bounds__(256)
void vtrans_kernel(const unsigned short* __restrict__ v,
                   unsigned short* __restrict__ vt) {
  const int bh = blockIdx.y;
  const int b = bh >> 4, h = bh & 15;
  const int s0 = blockIdx.x * 32;
  __shared__ unsigned short tile[32][136];  // 272B row stride: 16B-aligned rows
  const int t = threadIdx.x;
  for (int i = 0; i < 2; i++) {
    int c = t + i * 256;
    int s = c >> 4, dc = c & 15;
    *(short8*)&tile[s][dc * 8] =
        *(const short8*)(v + (size_t)(b * SEQ + s0 + s) * D_MODEL + h * HEAD_DIM + dc * 8);
  }
  __syncthreads();
  const int d = t >> 1, sh = (t & 1) * 16;
  unsigned short* dst = vt + ((size_t)bh * HEAD_DIM + d) * SEQ + s0 + sh;
  short8 r0, r1;
#pragma unroll
  for (int j = 0; j < 8; j++) r0[j] = tile[sh + j][d];
#pragma unroll
  for (int j = 0; j < 8; j++) r1[j] = tile[sh + 8 + j][d];
  *(short8*)dst = r0;
  *(short8*)(dst + 8) = r1;
}

// ---------------- Flash attention: Q-tile 64 (16 rows/wave), KV-tile 64 ------
__global__ __launch_bounds__(256)
void attn_kernel(const unsigned short* __restrict__ q,
                 const unsigned short* __restrict__ k,
                 const unsigned short* __restrict__ vt,
                 unsigned short* __restrict__ o) {
  const int bh = blockIdx.y;
  const int b = bh >> 4, h = bh & 15;
  const int q0 = blockIdx.x << 6;
  const int t = threadIdx.x, w = t >> 6, l = t & 63;
  const int lr = l & 15, lg = l >> 4;

  __shared__ unsigned short Ks[64 * 128];   // XOR-swizzled
  __shared__ unsigned short Ps[4][16 * 64]; // per-wave, XOR-swizzled

  short8 qf[4];
  {
    const unsigned short* qb =
        q + ((size_t)(b * SEQ + q0 + w * 16 + lr)) * D_MODEL + h * HEAD_DIM;
#pragma unroll
    for (int ks = 0; ks < 4; ks++) qf[ks] = *(const short8*)(qb + ks * 32 + lg * 8);
  }

  f32x4 oacc[8] = {};
  float mrow[4] = {-1e30f, -1e30f, -1e30f, -1e30f};
  float lrowv[4] = {0.f, 0.f, 0.f, 0.f};
  const float scl = 0.08838834764831845f;  // 1/sqrt(128)

  const unsigned short* kbase = k + (size_t)(b * SEQ) * D_MODEL + h * HEAD_DIM;
  const unsigned short* vtb = vt + (size_t)bh * HEAD_DIM * SEQ;
  unsigned short* pw = &Ps[w][0];

  for (int kv0 = 0; kv0 < SEQ; kv0 += 64) {
    // stage K tile (swizzled)
    for (int i = 0; i < 4; i++) {
      int c = t + i * 256;
      int row = c >> 4, dc = c & 15;
      short8 val = *(const short8*)(kbase + (size_t)(kv0 + row) * D_MODEL + dc * 8);
      int byo = ((row * 256 + dc * 16) ^ ((row & 7) << 4));
      *(short8*)((char*)Ks + byo) = val;
    }
    __syncthreads();

    // S = Q @ K^T  (16 x 64 per wave)
    f32x4 s[4] = {};
#pragma unroll
    for (int nf = 0; nf < 4; nf++) {
      int key = nf * 16 + lr;
#pragma unroll
      for (int ks = 0; ks < 4; ks++) {
        int byo = ((key * 256 + ks * 64 + lg * 16) ^ ((key & 7) << 4));
        short8 kf = *(const short8*)((char*)Ks + byo);
        s[nf] = __builtin_amdgcn_mfma_f32_16x16x32_bf16(qf[ks], kf, s[nf], 0, 0, 0);
      }
    }

    // online softmax (rows = lg*4 + j, cols spread over lanes lr & frags)
    float pm[4];
#pragma unroll
    for (int j = 0; j < 4; j++) {
      float mx = -1e30f;
#pragma unroll
      for (int nf = 0; nf < 4; nf++) {
        s[nf][j] *= scl;
        mx = fmaxf(mx, s[nf][j]);
      }
      mx = fmaxf(mx, __shfl_xor(mx, 1));
      mx = fmaxf(mx, __shfl_xor(mx, 2));
      mx = fmaxf(mx, __shfl_xor(mx, 4));
      mx = fmaxf(mx, __shfl_xor(mx, 8));
      pm[j] = mx;
    }
    float fs[4];
#pragma unroll
    for (int j = 0; j < 4; j++) {
      float mn = fmaxf(mrow[j], pm[j]);
      fs[j] = __expf(mrow[j] - mn);
      mrow[j] = mn;
    }
    float rs[4] = {0.f, 0.f, 0.f, 0.f};
#pragma unroll
    for (int nf = 0; nf < 4; nf++)
#pragma unroll
      for (int j = 0; j < 4; j++) {
        float p = __expf(s[nf][j] - mrow[j]);
        s[nf][j] = p;
        rs[j] += p;
      }
#pragma unroll
    for (int j = 0; j < 4; j++) {
      float r = rs[j];
      r += __shfl_xor(r, 1);
      r += __shfl_xor(r, 2);
      r += __shfl_xor(r, 4);
      r += __shfl_xor(r, 8);
      lrowv[j] = lrowv[j] * fs[j] + r;
    }
#pragma unroll
    for (int nf = 0; nf < 8; nf++)
#pragma unroll
      for (int j = 0; j < 4; j++) oacc[nf][j] *= fs[j];

    // P -> LDS (bf16, swizzled), then PV
#pragma unroll
    for (int nf = 0; nf < 4; nf++)
#pragma unroll
      for (int j = 0; j < 4; j++) {
        int row = lg * 4 + j, col = nf * 16 + lr;
        int byo = ((row * 128 + col * 2) ^ ((row & 7) << 4));
        *(unsigned short*)((char*)pw + byo) = f2b(s[nf][j]);
      }
    asm volatile("s_waitcnt lgkmcnt(0)" ::: "memory");
#pragma unroll
    for (int ks = 0; ks < 2; ks++) {
      int byo = ((lr * 128 + ks * 64 + lg * 16) ^ ((lr & 7) << 4));
      short8 pa = *(const short8*)((char*)pw + byo);
#pragma unroll
      for (int nf = 0; nf < 8; nf++) {
        short8 vf = *(const short8*)(vtb + (size_t)(nf * 16 + lr) * SEQ + kv0 +
                                     ks * 32 + lg * 8);
        oacc[nf] = __builtin_amdgcn_mfma_f32_16x16x32_bf16(pa, vf, oacc[nf], 0, 0, 0);
      }
    }
    __syncthreads();
  }

  unsigned short* ob =
      o + ((size_t)(b * SEQ + q0 + w * 16)) * D_MODEL + h * HEAD_DIM;
#pragma unroll
  for (int j = 0; j < 4; j++) {
    float inv = 1.0f / lrowv[j];
    int row = lg * 4 + j;
#pragma unroll
    for (int nf = 0; nf < 8; nf++) {
      int col = nf * 16 + lr;
      ob[(size_t)row * D_MODEL + col] = f2b(oacc[nf][j] * inv);
    }
  }
}

// ---------------- SwiGLU in-place on g: g[m][j] = g[m][j]*silu(g[m][j+8192]) -
__global__ __launch_bounds__(256)
void swiglu_kernel(unsigned short* __restrict__ g) {
  size_t i = (size_t)blockIdx.x * 256 + threadIdx.x;
  size_t m = i >> 10, jc = i & 1023;
  unsigned short* p1 = g + m * (2 * D_FF) + jc * 8;
  short8 aa = *(short8*)p1;
  short8 bb = *(short8*)(p1 + D_FF);
  short8 r;
#pragma unroll
  for (int jj = 0; jj < 8; jj++) {
    float x1 = b2f((unsigned short)aa[jj]);
    float x2 = b2f((unsigned short)bb[jj]);
    float sg = x2 / (1.0f + __expf(-x2));
    r[jj] = f2b(x1 * sg);
  }
  *(short8*)p1 = r;
}

// ---------------- host: launch sequence --------------------------------------
extern "C" void kernel_launch(void* const* d_in, const int* in_sizes, int n_in,
                              void* d_out, int out_size, void* d_ws,
                              size_t ws_size, hipStream_t stream) {
  (void)in_sizes; (void)n_in; (void)out_size; (void)ws_size;
  const float* x   = (const float*)d_in[0];
  const float* Wq  = (const float*)d_in[1];
  const float* bq  = (const float*)d_in[2];
  const float* Wk  = (const float*)d_in[3];
  const float* bk  = (const float*)d_in[4];
  const float* Wv  = (const float*)d_in[5];
  const float* bv  = (const float*)d_in[6];
  const float* Wo  = (const float*)d_in[7];
  const float* bo  = (const float*)d_in[8];
  const float* rot = (const float*)d_in[9];
  const float* n1w = (const float*)d_in[10];
  const float* n2w = (const float*)d_in[11];
  const float* W1  = (const float*)d_in[12];
  const float* b1  = (const float*)d_in[13];
  const float* W2  = (const float*)d_in[14];
  const float* b2  = (const float*)d_in[15];
  float* out = (float*)d_out;
  char* ws = (char*)d_ws;

  const size_t SZ_D2 = (size_t)D_MODEL * D_MODEL * 2;      // 8 MiB
  const size_t SZ_ACT = (size_t)M_TOK * D_MODEL * 2;        // 16 MiB
  const size_t SZ_W1 = (size_t)2 * D_FF * D_MODEL * 2;      // 64 MiB
  const size_t SZ_W2 = (size_t)D_MODEL * D_FF * 2;          // 32 MiB
  const size_t SZ_G = (size_t)M_TOK * 2 * D_FF * 2;         // 128 MiB

  size_t off = 0;
  auto alloc = [&](size_t sz) { size_t o = off; off += (sz + 255) & ~(size_t)255; return o; };
  unsigned short* wq_b = (unsigned short*)(ws + alloc(SZ_D2));
  unsigned short* wk_b = (unsigned short*)(ws + alloc(SZ_D2));
  unsigned short* wv_b = (unsigned short*)(ws + alloc(SZ_D2));
  unsigned short* wo_b = (unsigned short*)(ws + alloc(SZ_D2));
  unsigned short* w1_b = (unsigned short*)(ws + alloc(SZ_W1));
  unsigned short* w2_b = (unsigned short*)(ws + alloc(SZ_W2));
  float*          bqe  = (float*)(ws + alloc(D_MODEL * 4));
  unsigned short* h2_b = (unsigned short*)(ws + alloc(SZ_ACT));
  char* pool = ws + alloc(SZ_G);  // phase1: h,q,k,v,vt,o ; phase2: g
  unsigned short* h_b  = (unsigned short*)(pool);
  unsigned short* q_b  = (unsigned short*)(pool + SZ_ACT);
  unsigned short* k_b  = (unsigned short*)(pool + 2 * SZ_ACT);
  unsigned short* v_b  = (unsigned short*)(pool + 3 * SZ_ACT);
  unsigned short* vt_b = (unsigned short*)(pool + 4 * SZ_ACT);
  unsigned short* o_b  = (unsigned short*)(pool + 5 * SZ_ACT);
  unsigned short* g_b  = (unsigned short*)(pool);

  // weights -> bf16
  cvt_kernel<<<1024, 256, 0, stream>>>(Wq, wq_b, D_MODEL * D_MODEL / 8);
  cvt_kernel<<<1024, 256, 0, stream>>>(Wk, wk_b, D_MODEL * D_MODEL / 8);
  cvt_kernel<<<1024, 256, 0, stream>>>(Wv, wv_b, D_MODEL * D_MODEL / 8);
  cvt_kernel<<<1024, 256, 0, stream>>>(Wo, wo_b, D_MODEL * D_MODEL / 8);
  cvt_kernel<<<2048, 256, 0, stream>>>(W1, w1_b, 2 * D_FF * D_MODEL / 8);
  cvt_kernel<<<2048, 256, 0, stream>>>(W2, w2_b, D_MODEL * D_FF / 8);
  bqrot_kernel<<<8, 256, 0, stream>>>(bq, rot, bqe);

  // norm1 -> h
  rmsnorm_kernel<<<M_TOK, 256, 0, stream>>>(x, n1w, h_b);

  // QKV projections
  gemm_bt<0><<<dim3(16, 32), 256, 0, stream>>>(h_b, D_MODEL, wq_b, bqe, nullptr, q_b, D_MODEL, D_MODEL);
  gemm_bt<0><<<dim3(16, 32), 256, 0, stream>>>(h_b, D_MODEL, wk_b, bk, nullptr, k_b, D_MODEL, D_MODEL);
  gemm_bt<0><<<dim3(16, 32), 256, 0, stream>>>(h_b, D_MODEL, wv_b, bv, nullptr, v_b, D_MODEL, D_MODEL);

  // V transpose + attention
  vtrans_kernel<<<dim3(SEQ / 32, BATCH * N_HEADS), 256, 0, stream>>>(v_b, vt_b);
  attn_kernel<<<dim3(SEQ / 64, BATCH * N_HEADS), 256, 0, stream>>>(q_b, k_b, vt_b, o_b);

  // O projection + residual -> d_out (f32) holds x1
  gemm_bt<1><<<dim3(16, 32), 256, 0, stream>>>(o_b, D_MODEL, wo_b, bo, x, out, D_MODEL, D_MODEL);

  // norm2 -> h2
  rmsnorm_kernel<<<M_TOK, 256, 0, stream>>>(out, n2w, h2_b);

  // W1 -> g (bf16, 4096 x 16384)
  gemm_bt<0><<<dim3(128, 32), 256, 0, stream>>>(h2_b, D_MODEL, w1_b, b1, nullptr, g_b, 2 * D_FF, D_MODEL);

  // SwiGLU in-place (first 8192 cols of g become ffin)
  swiglu_kernel<<<(M_TOK * D_FF / 8) / 256, 256, 0, stream>>>(g_b);

  // W2 + residual(d_out) -> d_out
  gemm_bt<1><<<dim3(16, 32), 256, 0, stream>>>(g_b, 2 * D_FF, w2_b, b2, out, out, D_MODEL, D_FF);
}